// Round 5
// baseline (65.783 us; speedup 1.0000x reference)
//
#include <hip/hip_runtime.h>
#include <math.h>

#define D_DIM 1280
#define ODIM  510
#define KSTEPS 40           // 1280 / 32 granule-steps per plane row-block

typedef short bf16x8 __attribute__((ext_vector_type(8)));   // 8 bf16 = 4 VGPRs
typedef float f32x4  __attribute__((ext_vector_type(4)));

// pack two fp32 -> packed bf16 pair in ONE instruction (v_cvt_pk_bf16_f32, RNE).
// low16 = a, high16 = b; numerics validated rounds 1-4 (absmax identical).
__device__ __forceinline__ unsigned pk2(float a, float b) {
  unsigned r;
  asm("v_cvt_pk_bf16_f32 %0, %1, %2" : "=v"(r) : "v"(a), "v"(b));
  return r;
}

// Prep v4 (verbatim round-4): plane bytes in MFMA fragment order, LDS transpose
// so both global sides are coalesced; 320-thread blocks = exactly one task per
// thread per phase; 256 blocks = 32 row-blocks x 8 K-eighths.
__global__ __launch_bounds__(320, 1) void pcmd_prep(
    const float* __restrict__ X,        // [512][1280]
    const float* __restrict__ W,        // [2560][2] (first 1280 rows = Wp)
    unsigned short* __restrict__ Xbf,   // fragment-ordered planes
    unsigned short* __restrict__ A0,
    unsigned short* __restrict__ A1)
{
  __shared__ unsigned short sG[3][5][64][8];   // 15 KB

  const int R   = (int)blockIdx.x >> 3;   // row-block 0..31
  const int e   = (int)blockIdx.x & 7;    // K-eighth 0..7 (160 floats each)
  const int tid = threadIdx.x;            // 0..319

  // ---- phase 1: 320 tasks = 16 rows x 20 granules, one per thread ----
  {
    const int lr = tid / 20;              // local row 0..15
    const int gc = tid - lr * 20;         // granule-in-eighth 0..19
    const int s = gc >> 2, quad = gc & 3;
    const int prow = R * 16 + lr;         // plane row
    uint4 vx = {0,0,0,0}, v0 = {0,0,0,0}, v1 = {0,0,0,0};
    if (prow <= 510) {                    // plane row <- X row prow+1; 511 stays zero
      const float* px = X + (size_t)(prow + 1) * D_DIM + e * 160 + gc * 8;
      float4 x0 = *(const float4*)px;
      float4 x1 = *(const float4*)(px + 4);
      const float* pw = W + 2 * (e * 160 + gc * 8);
      float4 w0 = *(const float4*)(pw +  0);
      float4 w1 = *(const float4*)(pw +  4);
      float4 w2 = *(const float4*)(pw +  8);
      float4 w3 = *(const float4*)(pw + 12);
      vx.x = pk2(x0.x, x0.y);             vx.y = pk2(x0.z, x0.w);
      vx.z = pk2(x1.x, x1.y);             vx.w = pk2(x1.z, x1.w);
      v0.x = pk2(x0.x*w0.x, x0.y*w0.z);   v0.y = pk2(x0.z*w1.x, x0.w*w1.z);
      v0.z = pk2(x1.x*w2.x, x1.y*w2.z);   v0.w = pk2(x1.z*w3.x, x1.w*w3.z);
      v1.x = pk2(x0.x*w0.y, x0.y*w0.w);   v1.y = pk2(x0.z*w1.y, x0.w*w1.w);
      v1.z = pk2(x1.x*w2.y, x1.y*w2.w);   v1.w = pk2(x1.z*w3.y, x1.w*w3.w);
    }
    const int swzl = quad * 16 + ((lr + quad + 4 * s) & 15);   // bank-spread rotation
    *(uint4*)&sG[0][s][swzl][0] = vx;
    *(uint4*)&sG[1][s][swzl][0] = v0;
    *(uint4*)&sG[2][s][swzl][0] = v1;
  }
  __syncthreads();

  // ---- phase 2: 320 granules, one per thread, lane-linear coalesced stores ----
  {
    const int s = tid >> 6, l = tid & 63;
    const int quad = l >> 4, m = l & 15;
    const int swzl = quad * 16 + ((m + quad + 4 * s) & 15);
    const size_t go = ((size_t)((R * KSTEPS + e * 5 + s) * 64) + l) * 8;
    *(uint4*)(Xbf + go) = *(const uint4*)&sG[0][s][swzl][0];
    *(uint4*)(A0  + go) = *(const uint4*)&sG[1][s][swzl][0];
    *(uint4*)(A1  + go) = *(const uint4*)&sG[2][s][swzl][0];
  }
}

// GEMM: verbatim round-4 kernel (XCD swizzle, 4-wave split-K, depth-4 prefetch)
// except __launch_bounds__(256, 3): residency 3 blocks/CU -> capacity 768 >= 528,
// so ALL blocks start at t~0 and the 16-block scheduling tail (528 > 2*256)
// disappears. VGPR live set ~90 << 170 cap, no spill.
__global__ __launch_bounds__(256, 3) void pcmd_gemm(
    const unsigned short* __restrict__ Xbf,
    const unsigned short* __restrict__ A0,
    const unsigned short* __restrict__ A1,
    const float* __restrict__ b,
    float* __restrict__ out)            // [510][510][2]
{
  __shared__ float sR[4][2][16][17];

  // XCD swizzle: chunk tiles so each XCD owns 66 consecutive t (shared A-panels).
  const int t = ((int)blockIdx.x % 8) * 66 + (int)blockIdx.x / 8;   // 0..527
  int bi = (int)((65.0 - sqrt(4225.0 - 8.0 * (double)t)) * 0.5);
  {
    int s0 = bi * 32 - (bi * (bi - 1)) / 2;
    if (t < s0) { --bi; }
    int s1 = (bi + 1) * 32 - ((bi + 1) * bi) / 2;
    if (t >= s1) { ++bi; }
  }
  const int start = bi * 32 - (bi * (bi - 1)) / 2;
  const int bj = bi + (t - start);

  const int tid  = threadIdx.x;
  const int lane = tid & 63;
  const int wv   = tid >> 6;

  const unsigned short* pa0 = A0  + ((size_t)(bi * KSTEPS + wv * 10) * 64 + lane) * 8;
  const unsigned short* pa1 = A1  + ((size_t)(bi * KSTEPS + wv * 10) * 64 + lane) * 8;
  const unsigned short* pb  = Xbf + ((size_t)(bj * KSTEPS + wv * 10) * 64 + lane) * 8;

  bf16x8 ra0[4], ra1[4], rb[4];
  #pragma unroll
  for (int s = 0; s < 4; ++s) {
    ra0[s] = *(const bf16x8*)(pa0 + s * 512);
    ra1[s] = *(const bf16x8*)(pa1 + s * 512);
    rb[s]  = *(const bf16x8*)(pb  + s * 512);
  }

  f32x4 acc0 = {0.f, 0.f, 0.f, 0.f};
  f32x4 acc1 = {0.f, 0.f, 0.f, 0.f};

  #pragma unroll
  for (int s = 0; s < 10; ++s) {
    const int cur = s & 3;
    bf16x8 a0 = ra0[cur], a1 = ra1[cur], bb = rb[cur];
    if (s + 4 < 10) {
      ra0[cur] = *(const bf16x8*)(pa0 + (s + 4) * 512);
      ra1[cur] = *(const bf16x8*)(pa1 + (s + 4) * 512);
      rb[cur]  = *(const bf16x8*)(pb  + (s + 4) * 512);
    }
    acc0 = __builtin_amdgcn_mfma_f32_16x16x32_bf16(a0, bb, acc0, 0, 0, 0);
    acc1 = __builtin_amdgcn_mfma_f32_16x16x32_bf16(a1, bb, acc1, 0, 0, 0);
  }

  const int m = lane & 15, quad = lane >> 4;
  #pragma unroll
  for (int r = 0; r < 4; ++r) {
    sR[wv][0][quad * 4 + r][m] = acc0[r];
    sR[wv][1][quad * 4 + r][m] = acc1[r];
  }
  __syncthreads();

  const float b0 = b[0], b1 = b[1];
  const int il = tid >> 4, jl = tid & 15;

  {
    const int oi = bi * 16 + il, oj = bj * 16 + jl;
    if (oi < ODIM && oj < ODIM) {
      float2 v;
      v.x = sR[0][0][il][jl] + sR[1][0][il][jl] + sR[2][0][il][jl] + sR[3][0][il][jl] + b0;
      v.y = sR[0][1][il][jl] + sR[1][1][il][jl] + sR[2][1][il][jl] + sR[3][1][il][jl] + b1;
      *(float2*)(out + ((size_t)oi * ODIM + oj) * 2) = v;
    }
  }
  if (bi != bj) {
    const int oi = bj * 16 + il, oj = bi * 16 + jl;
    if (oi < ODIM && oj < ODIM) {
      float2 v;
      v.x = sR[0][0][jl][il] + sR[1][0][jl][il] + sR[2][0][jl][il] + sR[3][0][jl][il] + b0;
      v.y = sR[0][1][jl][il] + sR[1][1][jl][il] + sR[2][1][jl][il] + sR[3][1][jl][il] + b1;
      *(float2*)(out + ((size_t)oi * ODIM + oj) * 2) = v;
    }
  }
}

extern "C" void kernel_launch(void* const* d_in, const int* in_sizes, int n_in,
                              void* d_out, int out_size, void* d_ws, size_t ws_size,
                              hipStream_t stream) {
  const float* X = (const float*)d_in[0];
  const float* W = (const float*)d_in[1];
  const float* b = (const float*)d_in[2];
  float* out = (float*)d_out;
  (void)in_sizes; (void)n_in; (void)out_size; (void)ws_size;

  const size_t PLANE = (size_t)512 * D_DIM;        // elements per bf16 plane
  unsigned short* Xbf = (unsigned short*)d_ws;
  unsigned short* A0  = Xbf + PLANE;
  unsigned short* A1  = A0 + PLANE;

  hipLaunchKernelGGL(pcmd_prep, dim3(256), dim3(320), 0, stream, X, W, Xbf, A0, A1);
  hipLaunchKernelGGL(pcmd_gemm, dim3(528), dim3(256), 0, stream, Xbf, A0, A1, b, out);
}

// Round 6
// 65.360 us; speedup vs baseline: 1.0065x; 1.0065x over previous
//
#include <hip/hip_runtime.h>
#include <math.h>

#define D_DIM 1280
#define ODIM  510
#define KSTEPS 40           // 1280 / 32 granule-steps per plane row-block

typedef short bf16x8 __attribute__((ext_vector_type(8)));   // 8 bf16 = 4 VGPRs
typedef float f32x4  __attribute__((ext_vector_type(4)));

// pack two fp32 -> packed bf16 pair in ONE instruction (v_cvt_pk_bf16_f32, RNE).
// low16 = a, high16 = b; numerics validated rounds 1-5 (absmax identical).
__device__ __forceinline__ unsigned pk2(float a, float b) {
  unsigned r;
  asm("v_cvt_pk_bf16_f32 %0, %1, %2" : "=v"(r) : "v"(a), "v"(b));
  return r;
}

// Prep v4 (verbatim rounds 4-5): plane bytes in MFMA fragment order, LDS
// transpose so both global sides are coalesced; 320-thread blocks = exactly one
// task per thread per phase; 256 blocks = 32 row-blocks x 8 K-eighths.
__global__ __launch_bounds__(320, 1) void pcmd_prep(
    const float* __restrict__ X,        // [512][1280]
    const float* __restrict__ W,        // [2560][2] (first 1280 rows = Wp)
    unsigned short* __restrict__ Xbf,   // fragment-ordered planes
    unsigned short* __restrict__ A0,
    unsigned short* __restrict__ A1)
{
  __shared__ unsigned short sG[3][5][64][8];   // 15 KB

  const int R   = (int)blockIdx.x >> 3;   // row-block 0..31
  const int e   = (int)blockIdx.x & 7;    // K-eighth 0..7 (160 floats each)
  const int tid = threadIdx.x;            // 0..319

  // ---- phase 1: 320 tasks = 16 rows x 20 granules, one per thread ----
  {
    const int lr = tid / 20;              // local row 0..15
    const int gc = tid - lr * 20;         // granule-in-eighth 0..19
    const int s = gc >> 2, quad = gc & 3;
    const int prow = R * 16 + lr;         // plane row
    uint4 vx = {0,0,0,0}, v0 = {0,0,0,0}, v1 = {0,0,0,0};
    if (prow <= 510) {                    // plane row <- X row prow+1; 511 stays zero
      const float* px = X + (size_t)(prow + 1) * D_DIM + e * 160 + gc * 8;
      float4 x0 = *(const float4*)px;
      float4 x1 = *(const float4*)(px + 4);
      const float* pw = W + 2 * (e * 160 + gc * 8);
      float4 w0 = *(const float4*)(pw +  0);
      float4 w1 = *(const float4*)(pw +  4);
      float4 w2 = *(const float4*)(pw +  8);
      float4 w3 = *(const float4*)(pw + 12);
      vx.x = pk2(x0.x, x0.y);             vx.y = pk2(x0.z, x0.w);
      vx.z = pk2(x1.x, x1.y);             vx.w = pk2(x1.z, x1.w);
      v0.x = pk2(x0.x*w0.x, x0.y*w0.z);   v0.y = pk2(x0.z*w1.x, x0.w*w1.z);
      v0.z = pk2(x1.x*w2.x, x1.y*w2.z);   v0.w = pk2(x1.z*w3.x, x1.w*w3.z);
      v1.x = pk2(x0.x*w0.y, x0.y*w0.w);   v1.y = pk2(x0.z*w1.y, x0.w*w1.w);
      v1.z = pk2(x1.x*w2.y, x1.y*w2.w);   v1.w = pk2(x1.z*w3.y, x1.w*w3.w);
    }
    const int swzl = quad * 16 + ((lr + quad + 4 * s) & 15);   // bank-spread rotation
    *(uint4*)&sG[0][s][swzl][0] = vx;
    *(uint4*)&sG[1][s][swzl][0] = v0;
    *(uint4*)&sG[2][s][swzl][0] = v1;
  }
  __syncthreads();

  // ---- phase 2: 320 granules, one per thread, lane-linear coalesced stores ----
  {
    const int s = tid >> 6, l = tid & 63;
    const int quad = l >> 4, m = l & 15;
    const int swzl = quad * 16 + ((m + quad + 4 * s) & 15);
    const size_t go = ((size_t)((R * KSTEPS + e * 5 + s) * 64) + l) * 8;
    *(uint4*)(Xbf + go) = *(const uint4*)&sG[0][s][swzl][0];
    *(uint4*)(A0  + go) = *(const uint4*)&sG[1][s][swzl][0];
    *(uint4*)(A1  + go) = *(const uint4*)&sG[2][s][swzl][0];
  }
}

// GEMM v2: 8-wave split-K (512 threads). Each wave owns K/8 = 160 -> only 5
// granule-steps; all 15 fragment loads issued up-front (60 VGPR prefetch),
// halving the serial L2-latency chain vs the 4-wave/10-step version. Epilogue
// parallelized: threads 0-255 store the direct tile, 256-511 the transposed
// tile concurrently. XCD swizzle kept (528 % 8 == 0 -> bijective).
__global__ __launch_bounds__(512, 4) void pcmd_gemm(
    const unsigned short* __restrict__ Xbf,
    const unsigned short* __restrict__ A0,
    const unsigned short* __restrict__ A1,
    const float* __restrict__ b,
    float* __restrict__ out)            // [510][510][2]
{
  __shared__ float sR[8][2][16][17];    // 17.4 KB

  const int t = ((int)blockIdx.x % 8) * 66 + (int)blockIdx.x / 8;   // 0..527
  int bi = (int)((65.0 - sqrt(4225.0 - 8.0 * (double)t)) * 0.5);
  {
    int s0 = bi * 32 - (bi * (bi - 1)) / 2;
    if (t < s0) { --bi; }
    int s1 = (bi + 1) * 32 - ((bi + 1) * bi) / 2;
    if (t >= s1) { ++bi; }
  }
  const int start = bi * 32 - (bi * (bi - 1)) / 2;
  const int bj = bi + (t - start);

  const int tid  = threadIdx.x;         // 0..511
  const int lane = tid & 63;
  const int wv   = tid >> 6;            // K-eighth 0..7

  const unsigned short* pa0 = A0  + ((size_t)(bi * KSTEPS + wv * 5) * 64 + lane) * 8;
  const unsigned short* pa1 = A1  + ((size_t)(bi * KSTEPS + wv * 5) * 64 + lane) * 8;
  const unsigned short* pb  = Xbf + ((size_t)(bj * KSTEPS + wv * 5) * 64 + lane) * 8;

  // issue ALL fragment loads up-front: 15 x dwordx4 outstanding per lane
  bf16x8 ra0[5], ra1[5], rb[5];
  #pragma unroll
  for (int s = 0; s < 5; ++s) {
    ra0[s] = *(const bf16x8*)(pa0 + s * 512);
    ra1[s] = *(const bf16x8*)(pa1 + s * 512);
    rb[s]  = *(const bf16x8*)(pb  + s * 512);
  }

  f32x4 acc0 = {0.f, 0.f, 0.f, 0.f};
  f32x4 acc1 = {0.f, 0.f, 0.f, 0.f};
  #pragma unroll
  for (int s = 0; s < 5; ++s) {
    acc0 = __builtin_amdgcn_mfma_f32_16x16x32_bf16(ra0[s], rb[s], acc0, 0, 0, 0);
    acc1 = __builtin_amdgcn_mfma_f32_16x16x32_bf16(ra1[s], rb[s], acc1, 0, 0, 0);
  }

  const int m = lane & 15, quad = lane >> 4;
  #pragma unroll
  for (int r = 0; r < 4; ++r) {
    sR[wv][0][quad * 4 + r][m] = acc0[r];
    sR[wv][1][quad * 4 + r][m] = acc1[r];
  }
  __syncthreads();

  const float b0 = b[0], b1 = b[1];
  const int half = tid >> 8;            // 0: direct tile, 1: transposed tile
  const int il = (tid >> 4) & 15, jl = tid & 15;

  if (half == 0) {
    const int oi = bi * 16 + il, oj = bj * 16 + jl;
    if (oi < ODIM && oj < ODIM) {
      float2 v;
      v.x = (((sR[0][0][il][jl] + sR[1][0][il][jl]) + (sR[2][0][il][jl] + sR[3][0][il][jl]))
           + ((sR[4][0][il][jl] + sR[5][0][il][jl]) + (sR[6][0][il][jl] + sR[7][0][il][jl]))) + b0;
      v.y = (((sR[0][1][il][jl] + sR[1][1][il][jl]) + (sR[2][1][il][jl] + sR[3][1][il][jl]))
           + ((sR[4][1][il][jl] + sR[5][1][il][jl]) + (sR[6][1][il][jl] + sR[7][1][il][jl]))) + b1;
      *(float2*)(out + ((size_t)oi * ODIM + oj) * 2) = v;
    }
  } else if (bi != bj) {
    const int oi = bj * 16 + il, oj = bi * 16 + jl;
    if (oi < ODIM && oj < ODIM) {
      float2 v;
      v.x = (((sR[0][0][jl][il] + sR[1][0][jl][il]) + (sR[2][0][jl][il] + sR[3][0][jl][il]))
           + ((sR[4][0][jl][il] + sR[5][0][jl][il]) + (sR[6][0][jl][il] + sR[7][0][jl][il]))) + b0;
      v.y = (((sR[0][1][jl][il] + sR[1][1][jl][il]) + (sR[2][1][jl][il] + sR[3][1][jl][il]))
           + ((sR[4][1][jl][il] + sR[5][1][jl][il]) + (sR[6][1][jl][il] + sR[7][1][jl][il]))) + b1;
      *(float2*)(out + ((size_t)oi * ODIM + oj) * 2) = v;
    }
  }
}

extern "C" void kernel_launch(void* const* d_in, const int* in_sizes, int n_in,
                              void* d_out, int out_size, void* d_ws, size_t ws_size,
                              hipStream_t stream) {
  const float* X = (const float*)d_in[0];
  const float* W = (const float*)d_in[1];
  const float* b = (const float*)d_in[2];
  float* out = (float*)d_out;
  (void)in_sizes; (void)n_in; (void)out_size; (void)ws_size;

  const size_t PLANE = (size_t)512 * D_DIM;        // elements per bf16 plane
  unsigned short* Xbf = (unsigned short*)d_ws;
  unsigned short* A0  = Xbf + PLANE;
  unsigned short* A1  = A0 + PLANE;

  hipLaunchKernelGGL(pcmd_prep, dim3(256), dim3(320), 0, stream, X, W, Xbf, A0, A1);
  hipLaunchKernelGGL(pcmd_gemm, dim3(528), dim3(512), 0, stream, Xbf, A0, A1, b, out);
}